// Round 7
// baseline (552.679 us; speedup 1.0000x reference)
//
#include <hip/hip_runtime.h>
#include <hip/hip_bf16.h>

// RealISTFT = bf16 MFMA gather-GEMM with OLA folded into the K axis.
// out[b][o] = (1/env) * sum_{s=0..3} sum_f S[b][th-s][f] * bas2[j][s*1088+f]
//   th = (o+512)>>8, j = (o+512)&255
//   bas2[j][s*1088+f] = basis[j+256s][f] * window[j+256s]   (window folded in)
//   S rows stored at physical row t+1 (one leading zero row) so th-s=-1 reads zeros.
// gemm: A tile (136 rows x 32) staged once per 32-col k-chunk, shared by all 4
// sections via LDS row offset. B staged in TWO section-halves (16 KB instead of
// 32 KB) -> LDS 24.5 KB -> 4 blocks/CU (was ~2): inter-block overlap hides the
// per-barrier vmcnt(0) drain (m97 mechanism). 68 sub-steps, 32 MFMA/wave each.

#define NFFT   1024
#define NFREQ  513
#define TFR    4000
#define NB     16
#define HOP    256
#define OUTLEN 1023744   // (TFR-1)*HOP
#define KPAD   1088      // one section: real [0,513), imag (neg-sin) [544,1057)
#define IMB    544
#define PADR   4160      // physical S rows; logical t = phys-1
#define K2     4352      // 4*KPAD gather-K

typedef __bf16 bf16x8 __attribute__((ext_vector_type(8)));
typedef float  f32x4  __attribute__((ext_vector_type(4)));
typedef unsigned short ushort8 __attribute__((ext_vector_type(8)));

__device__ inline unsigned short f2bf(float x) {
    unsigned u = __float_as_uint(x);
    unsigned r = (u + 0x7FFFu + ((u >> 16) & 1u)) >> 16;   // RTN-even
    return (unsigned short)r;
}

// ---- kernel 1: S[b][t+1][k] bf16, transposed from [k][t] fp32 inputs ----
// (round-3 proven version; only the grid mapping changed: t-tiles are now the
// fastest-varying block dim so concurrent blocks stream contiguous t.)
__global__ __launch_bounds__(256) void prep_s(
        const float* __restrict__ mag, const float* __restrict__ cosp,
        const float* __restrict__ sinp, unsigned short* __restrict__ S) {
    const int f0 = blockIdx.y * 32, t0 = blockIdx.x * 64, b = blockIdx.z;
    __shared__ float Lr[32][65];
    __shared__ float Li[32][65];
    const int tid = threadIdx.x;
    const int tt = tid & 63, kq = tid >> 6;
    const size_t bst = (size_t)NFREQ * TFR;
    const float* magB = mag  + (size_t)b * bst;
    const float* cosB = cosp + (size_t)b * bst;
    const float* sinB = sinp + (size_t)b * bst;
    const int t = t0 + tt - 1;                      // logical frame index
    #pragma unroll
    for (int u = 0; u < 8; ++u) {
        const int kk = kq * 8 + u;
        const int f = f0 + kk;
        float vr = 0.f, vi = 0.f;
        if (f < NFREQ && t >= 0 && t < TFR) {
            const size_t i = (size_t)f * TFR + t;
            const float m = magB[i];
            vr = m * cosB[i];
            vi = m * sinB[i];
        }
        Lr[kk][tt] = vr;
        Li[kk][tt] = vi;
    }
    __syncthreads();
    const int tt2 = tid >> 2, kk0 = (tid & 3) * 8;
    ushort8 pr, pi;
    #pragma unroll
    for (int j = 0; j < 8; ++j) {
        pr[j] = f2bf(Lr[kk0 + j][tt2]);
        pi[j] = f2bf(Li[kk0 + j][tt2]);
    }
    unsigned short* rowp = S + ((size_t)b * PADR + t0 + tt2) * KPAD;
    *(ushort8*)(rowp + f0 + kk0)       = pr;
    *(ushort8*)(rowp + IMB + f0 + kk0) = pi;
}

// ---- kernel 2: gather basis bas2[j][s*1088+f] = basis[j+256s][f]*w[j+256s], bf16 ----
__global__ void build_basis2(const float* __restrict__ window,
                             unsigned short* __restrict__ bas2) {
    const int j = blockIdx.x;                        // 0..255
    const float step = 6.28318530717958647692f / (float)NFFT;
    #pragma unroll
    for (int sec = 0; sec < 4; ++sec) {
        const int n = j + 256 * sec;
        const float wv = window[n];
        for (int f = threadIdx.x; f < KPAD; f += 256) {
            float v = 0.f;
            if (f < NFREQ) {
                const float scale = (f == 0 || f == NFFT / 2) ? (1.f / NFFT) : (2.f / NFFT);
                v = cosf(step * (float)((n * f) & (NFFT - 1))) * scale * wv;
            } else if (f >= IMB && f < IMB + NFREQ) {
                const int ff = f - IMB;
                const float scale = (ff == 0 || ff == NFFT / 2) ? (1.f / NFFT) : (2.f / NFFT);
                v = -sinf(step * (float)((n * ff) & (NFFT - 1))) * scale * wv;
            }
            bas2[(size_t)j * K2 + sec * KPAD + f] = f2bf(v);
        }
    }
}

// ---- kernel 3: 128x128 bf16 MFMA gather-GEMM, A shared, B in section-halves ----
__global__ __launch_bounds__(256) void gemm_ola(
        const unsigned short* __restrict__ S, const unsigned short* __restrict__ bas2,
        const float* __restrict__ window, float* __restrict__ out) {
    // physical->logical swizzle: the two j-blocks sharing an S-tile (and consecutive
    // th-tiles) land on the same XCD's L2. phys%8 = XCD (heuristic), bijective.
    const int lin  = (blockIdx.z * 32 + blockIdx.y) * 2 + blockIdx.x;   // 0..1023, x-fastest
    const int logi = (lin & 7) * 128 + (lin >> 3);
    const int b    = logi >> 6;
    const int tile = (logi & 63) >> 1;
    const int j0   = (logi & 1) * 128;
    const int th0  = 2 + tile * 128;                 // output rows th0..th0+127

    // A: 136 rows x 32 shorts (64 B/row), rows 0..130 used = phys th0-2 .. th0+128.
    // B: 128 rows x 64 shorts (128 B/row) = ONE section-half (2 sections x 32 cols),
    //    16B-slot index (3-bit) XOR-swizzled by (row&7) for even bank spread.
    __shared__ unsigned short As[136 * 32];
    __shared__ unsigned short Bs[128 * 64];
    const int tid = threadIdx.x;
    const int lane = tid & 63, wave = tid >> 6;
    const int wr = wave >> 1, wc = wave & 1;
    const int quad = lane >> 4, r16 = lane & 15;

    const unsigned short* Sb  = S + (size_t)b * PADR * KPAD;
    const unsigned short* Ap0 = Sb + (size_t)(th0 - 2) * KPAD;   // phys rows th0-2 ..
    const unsigned short* Bp0 = bas2 + (size_t)j0 * K2;

    f32x4 acc[4][4];
    #pragma unroll
    for (int mi = 0; mi < 4; ++mi)
        #pragma unroll
        for (int ni = 0; ni < 4; ++ni)
            acc[mi][ni] = 0.f;

    for (int u = 0; u < 2 * (KPAD / 32); ++u) {      // 68 sub-steps
        const int fs = u >> 1, half = u & 1;
        const int kb = fs * 32;                      // short col within a section
        if (!half) {
            // ---- stage A: 544 x 16B slots, linear (persists across both halves) ----
            #pragma unroll
            for (int h = 0; h < 2; ++h) {
                const int slot = h * 256 + tid;      // 0..511
                const int row = slot >> 2, c16 = slot & 3;
                __builtin_amdgcn_global_load_lds(
                    (const __attribute__((address_space(1))) void*)(Ap0 + (size_t)row * KPAD + kb + c16 * 8),
                    (__attribute__((address_space(3))) void*)(As + slot * 8),
                    16, 0, 0);
            }
            if (tid < 32) {                          // slots 512..543 -> rows 128..135
                const int slot = 512 + tid;
                const int row = slot >> 2, c16 = slot & 3;
                __builtin_amdgcn_global_load_lds(
                    (const __attribute__((address_space(1))) void*)(Ap0 + (size_t)row * KPAD + kb + c16 * 8),
                    (__attribute__((address_space(3))) void*)(As + slot * 8),
                    16, 0, 0);
            }
        }
        // ---- stage B half: 1024 x 16B slots; dest linear, source slot8 ^= (row&7) ----
        #pragma unroll
        for (int h = 0; h < 4; ++h) {
            const int slot = h * 256 + tid;          // 0..1023
            const int row  = slot >> 3;              // 0..127
            const int c    = (slot & 7) ^ (row & 7); // content slot: [sec_local(2)][c16(4)]
            const int sl   = c >> 2, c16 = c & 3;
            __builtin_amdgcn_global_load_lds(
                (const __attribute__((address_space(1))) void*)(Bp0 + (size_t)row * K2 + (2 * half + sl) * KPAD + kb + c16 * 8),
                (__attribute__((address_space(3))) void*)(Bs + slot * 8),
                16, 0, 0);
        }
        __syncthreads();
        #pragma unroll
        for (int sl = 0; sl < 2; ++sl) {
            const int s = 2 * half + sl;             // global section 0..3
            bf16x8 af[4], bfr[4];
            #pragma unroll
            for (int mi = 0; mi < 4; ++mi)
                af[mi] = *(const bf16x8*)(As + (wr * 64 + mi * 16 + r16 + 3 - s) * 32 + quad * 8);
            #pragma unroll
            for (int ni = 0; ni < 4; ++ni)
                bfr[ni] = *(const bf16x8*)(Bs + (wc * 64 + ni * 16 + r16) * 64
                                              + (((sl * 4 + quad) ^ (r16 & 7)) * 8));
            #pragma unroll
            for (int mi = 0; mi < 4; ++mi)
                #pragma unroll
                for (int ni = 0; ni < 4; ++ni)
                    acc[mi][ni] = __builtin_amdgcn_mfma_f32_16x16x32_bf16(
                        af[mi], bfr[ni], acc[mi][ni], 0, 0, 0);
        }
        __syncthreads();
    }

    // Epilogue: out[th*256 + j - 512] = acc / win_env(th,j). Exactly-once, coalesced.
    float* outB = out + (size_t)b * OUTLEN;
    float wsq[4][4];
    #pragma unroll
    for (int ni = 0; ni < 4; ++ni) {
        const int j = j0 + wc * 64 + ni * 16 + r16;
        #pragma unroll
        for (int k = 0; k < 4; ++k) {
            const float w = window[j + 256 * k];
            wsq[ni][k] = w * w;
        }
    }
    const int thb = th0 + wr * 64 + quad * 4;
    if (th0 >= 3 && th0 + 127 <= TFR - 1) {
        // interior tiles (1..30): all 4 env terms valid for every row
        float inv[4];
        #pragma unroll
        for (int ni = 0; ni < 4; ++ni)
            inv[ni] = 1.f / (wsq[ni][0] + wsq[ni][1] + wsq[ni][2] + wsq[ni][3] + 1e-11f);
        #pragma unroll
        for (int ni = 0; ni < 4; ++ni) {
            const int j = j0 + wc * 64 + ni * 16 + r16;
            #pragma unroll
            for (int mi = 0; mi < 4; ++mi) {
                #pragma unroll
                for (int reg = 0; reg < 4; ++reg) {
                    const int th = thb + mi * 16 + reg;
                    outB[th * HOP + j - 512] = acc[mi][ni][reg] * inv[ni];
                }
            }
        }
    } else {
        // edge tiles (0 and 31): mask th and the env terms per element
        #pragma unroll
        for (int ni = 0; ni < 4; ++ni) {
            const int j = j0 + wc * 64 + ni * 16 + r16;
            #pragma unroll
            for (int mi = 0; mi < 4; ++mi) {
                #pragma unroll
                for (int reg = 0; reg < 4; ++reg) {
                    const int th = thb + mi * 16 + reg;
                    if (th <= TFR) {                       // th in [2,4000]
                        float env = 1e-11f;
                        #pragma unroll
                        for (int k = 0; k < 4; ++k)
                            if ((unsigned)(th - k) < (unsigned)TFR) env += wsq[ni][k];
                        outB[th * HOP + j - 512] = acc[mi][ni][reg] / env;
                    }
                }
            }
        }
    }
}

extern "C" void kernel_launch(void* const* d_in, const int* in_sizes, int n_in,
                              void* d_out, int out_size, void* d_ws, size_t ws_size,
                              hipStream_t stream) {
    const float* mag    = (const float*)d_in[0];
    const float* cosp   = (const float*)d_in[1];
    const float* sinp   = (const float*)d_in[2];
    const float* window = (const float*)d_in[3];
    float* out = (float*)d_out;

    unsigned short* S    = (unsigned short*)d_ws;                      // 16*4160*1088*2 B
    unsigned short* bas2 = S + (size_t)NB * PADR * KPAD;               // 256*4352*2 B

    prep_s<<<dim3(PADR / 64, 17, NB), 256, 0, stream>>>(mag, cosp, sinp, S);
    build_basis2<<<256, 256, 0, stream>>>(window, bas2);
    gemm_ola<<<dim3(2, 32, NB), 256, 0, stream>>>(S, bas2, window, out);
    // out is written exactly once per element: no memset, no normalize pass.
}

// Round 9
// 543.398 us; speedup vs baseline: 1.0171x; 1.0171x over previous
//
#include <hip/hip_runtime.h>
#include <hip/hip_bf16.h>

// RealISTFT = bf16 MFMA gather-GEMM with OLA folded into the K axis.
// out[b][o] = (1/env) * sum_{s=0..3} sum_f S[b][th-s][f] * bas2[j][s*KPAD+f]
//   th = (o+512)>>8, j = (o+512)&255
//   bas2[j][s*KPAD+f] = basis[j+256s][f] * window[j+256s]   (window folded in)
//   S rows stored at physical row t+1 (one leading zero row) so th-s=-1 reads zeros.
// Layout: KPAD=1152 (row stride 2304B = 18 lines), real [0,513), imag [576,1089).
//   -> every 128B line of S is written by exactly ONE prep_s block (no cross-XCD
//      half-line false sharing; that was prep_s's 2.6 TB/s cap).
// gemm: round-6 structure (A tile shared across the 4 OLA sections, full-B LDS,
//   34 K-steps) with chunks 17 and 35 (all-zero cols) skipped -> still 34 steps.

#define NFFT   1024
#define NFREQ  513
#define TFR    4000
#define NB     16
#define HOP    256
#define OUTLEN 1023744   // (TFR-1)*HOP
#define KPAD   1152      // one section: real [0,513), imag (neg-sin) [576,1089)
#define IMB    576
#define PADR   4160      // physical S rows; logical t = phys-1
#define K2     4608      // 4*KPAD gather-K

typedef __bf16 bf16x8 __attribute__((ext_vector_type(8)));
typedef float  f32x4  __attribute__((ext_vector_type(4)));
typedef unsigned short ushort8 __attribute__((ext_vector_type(8)));

__device__ inline unsigned short f2bf(float x) {
    unsigned u = __float_as_uint(x);
    unsigned r = (u + 0x7FFFu + ((u >> 16) & 1u)) >> 16;   // RTN-even
    return (unsigned short)r;
}

// ---- kernel 1: S[b][t+1][k] bf16, transposed from [k][t] fp32 inputs ----
// grid: (65 t-tiles, 9 f-tiles of 64, NB). Physical row = logical t + 1.
// Each 4-lane group writes 128B contiguous, 128B-aligned: lines are block-private.
__global__ __launch_bounds__(256) void prep_s(
        const float* __restrict__ mag, const float* __restrict__ cosp,
        const float* __restrict__ sinp, unsigned short* __restrict__ S) {
    const int t0 = blockIdx.x * 64, f0 = blockIdx.y * 64, b = blockIdx.z;
    __shared__ float Lr[64][65];
    __shared__ float Li[64][65];
    const int tid = threadIdx.x;
    const int tt = tid & 63, kq = tid >> 6;
    const size_t bst = (size_t)NFREQ * TFR;
    const float* magB = mag  + (size_t)b * bst;
    const float* cosB = cosp + (size_t)b * bst;
    const float* sinB = sinp + (size_t)b * bst;
    const int t = t0 + tt - 1;                      // logical frame index
    #pragma unroll
    for (int u = 0; u < 16; ++u) {
        const int fl = kq * 16 + u;                 // 0..63
        const int f = f0 + fl;
        float vr = 0.f, vi = 0.f;
        if (f < NFREQ && t >= 0 && t < TFR) {
            const size_t i = (size_t)f * TFR + t;
            const float m = magB[i];
            vr = m * cosB[i];
            vi = m * sinB[i];
        }
        Lr[fl][tt] = vr;
        Li[fl][tt] = vi;
    }
    __syncthreads();
    const int tt2 = tid >> 2, kk0 = (tid & 3) * 16;
    ushort8 pr0, pr1, pi0, pi1;
    #pragma unroll
    for (int j = 0; j < 8; ++j) {
        pr0[j] = f2bf(Lr[kk0 + j][tt2]);
        pr1[j] = f2bf(Lr[kk0 + 8 + j][tt2]);
        pi0[j] = f2bf(Li[kk0 + j][tt2]);
        pi1[j] = f2bf(Li[kk0 + 8 + j][tt2]);
    }
    unsigned short* rowp = S + ((size_t)b * PADR + t0 + tt2) * KPAD;
    *(ushort8*)(rowp + f0 + kk0)           = pr0;
    *(ushort8*)(rowp + f0 + kk0 + 8)       = pr1;
    *(ushort8*)(rowp + IMB + f0 + kk0)     = pi0;
    *(ushort8*)(rowp + IMB + f0 + kk0 + 8) = pi1;
}

// ---- kernel 2: gather basis bas2[j][s*KPAD+f] = basis[j+256s][f]*w[j+256s], bf16 ----
__global__ void build_basis2(const float* __restrict__ window,
                             unsigned short* __restrict__ bas2) {
    const int j = blockIdx.x;                        // 0..255
    const float step = 6.28318530717958647692f / (float)NFFT;
    #pragma unroll
    for (int sec = 0; sec < 4; ++sec) {
        const int n = j + 256 * sec;
        const float wv = window[n];
        for (int f = threadIdx.x; f < KPAD; f += 256) {
            float v = 0.f;
            if (f < NFREQ) {
                const float scale = (f == 0 || f == NFFT / 2) ? (1.f / NFFT) : (2.f / NFFT);
                v = cosf(step * (float)((n * f) & (NFFT - 1))) * scale * wv;
            } else if (f >= IMB && f < IMB + NFREQ) {
                const int ff = f - IMB;
                const float scale = (ff == 0 || ff == NFFT / 2) ? (1.f / NFFT) : (2.f / NFFT);
                v = -sinf(step * (float)((n * ff) & (NFFT - 1))) * scale * wv;
            }
            bas2[(size_t)j * K2 + sec * KPAD + f] = f2bf(v);
        }
    }
}

// ---- kernel 3: 128x128 bf16 MFMA gather-GEMM, A-tile shared across 4 sections ----
__global__ __launch_bounds__(256) void gemm_ola(
        const unsigned short* __restrict__ S, const unsigned short* __restrict__ bas2,
        const float* __restrict__ window, float* __restrict__ out) {
    // physical->logical swizzle: the two j-blocks sharing an S-tile (and consecutive
    // th-tiles) land on the same XCD's L2. phys%8 = XCD (heuristic), bijective.
    const int lin  = (blockIdx.z * 32 + blockIdx.y) * 2 + blockIdx.x;   // 0..1023, x-fastest
    const int logi = (lin & 7) * 128 + (lin >> 3);
    const int b    = logi >> 6;
    const int tile = (logi & 63) >> 1;
    const int j0   = (logi & 1) * 128;
    const int th0  = 2 + tile * 128;                 // output rows th0..th0+127

    // A: 136 rows x 32 shorts (64 B/row), rows 0..130 used = phys th0-2 .. th0+128.
    // B: 128 rows x 128 shorts (256 B/row), 16B-slot index XOR-swizzled by (row&7).
    __shared__ unsigned short As[136 * 32];
    __shared__ unsigned short Bs[128 * 128];
    const int tid = threadIdx.x;
    const int lane = tid & 63, wave = tid >> 6;
    const int wr = wave >> 1, wc = wave & 1;
    const int quad = lane >> 4, r16 = lane & 15;

    const unsigned short* Sb  = S + (size_t)b * PADR * KPAD;
    const unsigned short* Ap0 = Sb + (size_t)(th0 - 2) * KPAD;   // phys rows th0-2 ..
    const unsigned short* Bp0 = bas2 + (size_t)j0 * K2;

    f32x4 acc[4][4];
    #pragma unroll
    for (int mi = 0; mi < 4; ++mi)
        #pragma unroll
        for (int ni = 0; ni < 4; ++ni)
            acc[mi][ni] = 0.f;

    for (int q = 0; q < 34; ++q) {                   // skip all-zero chunks 17 and 35
        const int fs = q + (q >= 17);
        const int kb = fs * 32;                      // short col within a section
        // ---- stage A: 544 x 16B slots, linear ----
        #pragma unroll
        for (int h = 0; h < 2; ++h) {
            const int slot = h * 256 + tid;          // 0..511
            const int row = slot >> 2, c16 = slot & 3;
            __builtin_amdgcn_global_load_lds(
                (const __attribute__((address_space(1))) void*)(Ap0 + (size_t)row * KPAD + kb + c16 * 8),
                (__attribute__((address_space(3))) void*)(As + slot * 8),
                16, 0, 0);
        }
        if (tid < 32) {                              // slots 512..543 -> rows 128..135
            const int slot = 512 + tid;
            const int row = slot >> 2, c16 = slot & 3;
            __builtin_amdgcn_global_load_lds(
                (const __attribute__((address_space(1))) void*)(Ap0 + (size_t)row * KPAD + kb + c16 * 8),
                (__attribute__((address_space(3))) void*)(As + slot * 8),
                16, 0, 0);
        }
        // ---- stage B: 2048 x 16B slots; dest linear, source slot16 ^= (row&7) ----
        #pragma unroll
        for (int h = 0; h < 8; ++h) {
            const int slot = h * 256 + tid;          // 0..2047
            const int row  = slot >> 4;              // 0..127
            const int m16  = (slot & 15) ^ (row & 7);// content 16B-slot index
            const int sec  = m16 >> 2, c16 = m16 & 3;
            __builtin_amdgcn_global_load_lds(
                (const __attribute__((address_space(1))) void*)(Bp0 + (size_t)row * K2 + sec * KPAD + kb + c16 * 8),
                (__attribute__((address_space(3))) void*)(Bs + slot * 8),
                16, 0, 0);
        }
        __syncthreads();
        #pragma unroll
        for (int s = 0; s < 4; ++s) {
            bf16x8 af[4], bfr[4];
            #pragma unroll
            for (int mi = 0; mi < 4; ++mi)
                af[mi] = *(const bf16x8*)(As + (wr * 64 + mi * 16 + r16 + 3 - s) * 32 + quad * 8);
            #pragma unroll
            for (int ni = 0; ni < 4; ++ni)
                bfr[ni] = *(const bf16x8*)(Bs + (wc * 64 + ni * 16 + r16) * 128
                                              + (((s * 4 + quad) ^ (r16 & 7)) * 8));
            #pragma unroll
            for (int mi = 0; mi < 4; ++mi)
                #pragma unroll
                for (int ni = 0; ni < 4; ++ni)
                    acc[mi][ni] = __builtin_amdgcn_mfma_f32_16x16x32_bf16(
                        af[mi], bfr[ni], acc[mi][ni], 0, 0, 0);
        }
        __syncthreads();
    }

    // Epilogue: out[th*256 + j - 512] = acc / win_env(th,j). Exactly-once, coalesced.
    float* outB = out + (size_t)b * OUTLEN;
    float wsq[4][4];
    #pragma unroll
    for (int ni = 0; ni < 4; ++ni) {
        const int j = j0 + wc * 64 + ni * 16 + r16;
        #pragma unroll
        for (int k = 0; k < 4; ++k) {
            const float w = window[j + 256 * k];
            wsq[ni][k] = w * w;
        }
    }
    const int thb = th0 + wr * 64 + quad * 4;
    if (th0 >= 3 && th0 + 127 <= TFR - 1) {
        // interior tiles (1..30): all 4 env terms valid for every row
        float inv[4];
        #pragma unroll
        for (int ni = 0; ni < 4; ++ni)
            inv[ni] = 1.f / (wsq[ni][0] + wsq[ni][1] + wsq[ni][2] + wsq[ni][3] + 1e-11f);
        #pragma unroll
        for (int ni = 0; ni < 4; ++ni) {
            const int j = j0 + wc * 64 + ni * 16 + r16;
            #pragma unroll
            for (int mi = 0; mi < 4; ++mi) {
                #pragma unroll
                for (int reg = 0; reg < 4; ++reg) {
                    const int th = thb + mi * 16 + reg;
                    outB[th * HOP + j - 512] = acc[mi][ni][reg] * inv[ni];
                }
            }
        }
    } else {
        // edge tiles (0 and 31): mask th and the env terms per element
        #pragma unroll
        for (int ni = 0; ni < 4; ++ni) {
            const int j = j0 + wc * 64 + ni * 16 + r16;
            #pragma unroll
            for (int mi = 0; mi < 4; ++mi) {
                #pragma unroll
                for (int reg = 0; reg < 4; ++reg) {
                    const int th = thb + mi * 16 + reg;
                    if (th <= TFR) {                       // th in [2,4000]
                        float env = 1e-11f;
                        #pragma unroll
                        for (int k = 0; k < 4; ++k)
                            if ((unsigned)(th - k) < (unsigned)TFR) env += wsq[ni][k];
                        outB[th * HOP + j - 512] = acc[mi][ni][reg] / env;
                    }
                }
            }
        }
    }
}

extern "C" void kernel_launch(void* const* d_in, const int* in_sizes, int n_in,
                              void* d_out, int out_size, void* d_ws, size_t ws_size,
                              hipStream_t stream) {
    const float* mag    = (const float*)d_in[0];
    const float* cosp   = (const float*)d_in[1];
    const float* sinp   = (const float*)d_in[2];
    const float* window = (const float*)d_in[3];
    float* out = (float*)d_out;

    unsigned short* S    = (unsigned short*)d_ws;                      // 16*4160*1152*2 B
    unsigned short* bas2 = S + (size_t)NB * PADR * KPAD;               // 256*4608*2 B

    prep_s<<<dim3(PADR / 64, 9, NB), 256, 0, stream>>>(mag, cosp, sinp, S);
    build_basis2<<<256, 256, 0, stream>>>(window, bas2);
    gemm_ola<<<dim3(2, 32, NB), 256, 0, stream>>>(S, bas2, window, out);
    // out is written exactly once per element: no memset, no normalize pass.
}